// Round 12
// baseline (586.219 us; speedup 1.0000x reference)
//
#include <hip/hip_runtime.h>
#include <hip/hip_bf16.h>

typedef unsigned short u16;
typedef unsigned int   u32;
typedef unsigned long long u64;
typedef __attribute__((ext_vector_type(8))) short bf16x8;
typedef __attribute__((ext_vector_type(4))) float f32x4;
typedef __attribute__((ext_vector_type(16))) float f32x16;
typedef __attribute__((ext_vector_type(2))) unsigned int u32x2;

#define MFMA16(a,b,c) __builtin_amdgcn_mfma_f32_16x16x32_bf16(a,b,c,0,0,0)
#define MFMA32(a,b,c) __builtin_amdgcn_mfma_f32_32x32x16_bf16(a,b,c,0,0,0)

// ---- problem dims ----
#define NV_   321
#define B_    16
#define L_    512
#define D_    128
#define P_    64
#define E_    8
#define H_    512
#define NRW   5136        // B*NV
#define NTOK  328704      // NRW*P
#define DP_   8192        // D*P
#define NBUCK 329728      // NTOK + 8*128 padding
#define NBLK_SLOT 2576    // max expert blocks per slot

static __device__ __forceinline__ u16 f2bf(float f){
  __hip_bfloat16 h = __float2bfloat16(f);
  return *reinterpret_cast<u16*>(&h);
}

static __device__ __forceinline__ u32 bfadd2(u32 a, u32 b){
  float lo = __uint_as_float(a<<16)           + __uint_as_float(b<<16);
  float hi = __uint_as_float(a&0xffff0000u)   + __uint_as_float(b&0xffff0000u);
  return (u32)f2bf(lo) | ((u32)f2bf(hi)<<16);
}

// sigma-form tanh-GELU: x*sigma(1.5958x(1+0.044715x^2)); exp2 maps to v_exp_f32
static __device__ __forceinline__ float gelu_f(float x){
  float x2 = x*x;
  float p  = __builtin_fmaf(-0.1029433f, x2, -2.3022083f);
  float a  = x*p;
  float en = exp2f(a);
  float r  = __builtin_amdgcn_rcpf(1.0f + en);
  return x*r;
}

// ============ workspace layout (bytes) — end ~249.4 MiB (budget 256 MiB) ============
// Permanent (live across expert dispatch):
static constexpr size_t alup(size_t x){ return (x + 255) & ~(size_t)255; }
static constexpr size_t OFF_MEAN = 0;
static constexpr size_t OFF_RSTD = OFF_MEAN + alup((size_t)NRW*4);
static constexpr size_t OFF_STD  = OFF_RSTD + alup((size_t)NRW*4);
static constexpr size_t OFF_MEAND= OFF_STD  + alup((size_t)NRW*4);
static constexpr size_t OFF_RSTDD= OFF_MEAND+ alup((size_t)NRW*8);
static constexpr size_t OFF_WVG  = OFF_RSTDD+ alup((size_t)NRW*8);
static constexpr size_t OFF_PEG  = OFF_WVG  + alup((size_t)16*8*8);
static constexpr size_t OFF_W1T  = OFF_PEG  + alup((size_t)P_*E_*8);
static constexpr size_t OFF_W2T  = OFF_W1T  + alup((size_t)E_*H_*D_*2);
static constexpr size_t OFF_WHT  = OFF_W2T  + alup((size_t)E_*D_*H_*2);
static constexpr size_t OFF_T    = OFF_WHT  + alup((size_t)96*DP_*2);      // tokens bf16; later ALIASED as dec8
static constexpr size_t OFF_CNTR = OFF_T    + alup((size_t)NTOK*D_*2);
static constexpr size_t OFF_BTOK = OFF_CNTR + alup((size_t)1024);
static constexpr size_t OFF_BGT  = OFF_BTOK + alup((size_t)2*NBUCK*4);
static constexpr size_t OFF_OUT  = OFF_BGT  + alup((size_t)2*NBUCK*4);     // slot-0 outputs bf16 [token][d]
static constexpr size_t OFF_OUT2 = OFF_OUT  + alup((size_t)NTOK*D_*2);     // slot-1 outputs bf16 [token][d]
// Transients (dead before first expert write) — ALIAS the OUT2 region:
static constexpr size_t OFF_XT   = OFF_OUT2;
static constexpr size_t OFF_PE   = OFF_XT   + alup((size_t)NRW*L_*4);
static constexpr size_t OFF_TOPI = OFF_PE   + alup((size_t)P_*D_*4);
static constexpr size_t OFF_GATE = OFF_TOPI + alup((size_t)NTOK*4);
static constexpr size_t OFF_PG   = OFF_GATE + alup((size_t)NTOK*8);
static constexpr size_t OFF_PI   = OFF_PG   + alup((size_t)NRW*12*4);
static_assert(OFF_PI + (size_t)NRW*16*4 <= OFF_OUT2 + (size_t)NTOK*D_*2,
              "transients must fit inside outg2 alias region");

// ci ints at OFF_CNTR+128: [16..23]=cur1 [24..31]=cur2
// [32..40]=start1 [41..49]=start2 [50..58]=bstart1 [59..67]=bstart2
// NOTE: no memset needed — k_aux fully writes [16..67] before any reader.

// ============ kernels ============

// merged x-transpose (blocks [0,2816)) + weight-prep (blocks [2816,4609)) —
// independent work, same 256-thread (32,8) shape; overlap in one dispatch.
__global__ void k_xtprep(const float* __restrict__ x, float* __restrict__ xT,
                         const float* __restrict__ Wval, const float* __restrict__ Wg,
                         const float* __restrict__ W1, const float* __restrict__ W2,
                         const float* __restrict__ Wh,
                         float* __restrict__ pef, double* __restrict__ Wvg,
                         double* __restrict__ peg,
                         u16* __restrict__ W1T, u16* __restrict__ W2T,
                         u16* __restrict__ WhT2){
  __shared__ float tile[32][33];
  int blk = blockIdx.x;
  int tx = threadIdx.x, ty = threadIdx.y;
  int t = ty*32 + tx;
  if(blk < 2816){
    // ---- x transpose: decode (bx,by,bz) from former dim3(11,16,16) grid ----
    int bz = blk/176, rem = blk - bz*176;
    int by = rem/11,  bx  = rem - by*11;
    int b = bz;
    int v0 = bx*32, l0 = by*32;
    for(int i=ty;i<32;i+=8){
      int l = l0+i, v = v0+tx;
      tile[i][tx] = (v<NV_) ? x[((size_t)b*L_ + l)*NV_ + v] : 0.f;
    }
    __syncthreads();
    for(int i=ty;i<32;i+=8){
      int v = v0+i, l = l0+tx;
      if(v<NV_) xT[((size_t)(b*NV_+v))*L_ + l] = tile[tx][i];
    }
    return;
  }
  int bb = blk - 2816;   // weight-prep block id (0..1792)
  if(bb == 0){
    for(int i=t;i<8192;i+=256){
      int p = i>>7, d = i&127, k = d>>1;
      double div = exp(-(double)(2*k) * (9.210340371976184 /128.0)); // ln(10000)/128
      double ang = (double)p * div;
      double v = (d&1) ? cos(ang) : sin(ang);
      pef[i] = (float)v;
    }
    __syncthreads();
    if(t<128){
      int j = t>>3, e = t&7;
      double acc = 0.0;
      for(int d=0;d<128;d++) acc += (double)Wval[j*128+d] * (double)Wg[d*8+e];
      Wvg[t] = acc;
    }
    for(int q=t;q<512;q+=256){
      int p = q>>3, e = q&7;
      double acc = 0.0;
      for(int d=0;d<128;d++) acc += (double)pef[p*128+d] * (double)Wg[d*8+e];
      peg[q] = acc;
    }
    return;
  }
  if(bb < 1025){
    // W1: R=128,C=512, tiles (16 x 4); W2: R=512,C=128, tiles (4 x 16)
    bool isW1 = (bb < 513);
    int rem = isW1 ? (bb-1) : (bb-513);
    int e = rem >> 6, r6 = rem & 63;
    int R = isW1 ? 128 : 512, C = isW1 ? 512 : 128;
    int c0 = (isW1 ? (r6 & 15) : (r6 & 3))*32;
    int r0 = (isW1 ? (r6 >> 4) : (r6 >> 2))*32;
    const float* src = (isW1 ? W1 : W2) + (size_t)e*R*C;
    u16* dst = (isW1 ? W1T : W2T) + (size_t)e*R*C;
    for(int i=ty;i<32;i+=8){
      int r=r0+i, c=c0+tx;
      tile[i][tx] = (r<R && c<C) ? src[(size_t)r*C+c] : 0.f;
    }
    __syncthreads();
    for(int i=ty;i<32;i+=8){
      int c=c0+i, r=r0+tx;
      if(c<C && r<R) dst[(size_t)c*R + r] = f2bf(tile[tx][i]);
    }
    return;
  }
  {
    int rem = bb - 1025;
    int p = rem / 12, rr = rem - p*12;
    int d0 = (rr & 3)*32, o0 = (rr >> 2)*32;
    for(int i=ty;i<32;i+=8){
      int r = (d0+i)*64 + p;
      tile[i][tx] = Wh[(size_t)r*96 + o0 + tx];
    }
    __syncthreads();
    for(int i=ty;i<32;i+=8){
      int o = o0+i;
      WhT2[(size_t)o*DP_ + p*128 + d0 + tx] = f2bf(tile[tx][i]);
    }
  }
}

__global__ void k_stats(const float* __restrict__ xT, float* meanp, float* rstdp, float* stdp,
                        double* meand, double* rstdd){
  __shared__ double s1[256], s2[256];
  int r = blockIdx.x, t = threadIdx.x;
  double a = (double)xT[(size_t)r*L_ + t], b = (double)xT[(size_t)r*L_ + 256 + t];
  s1[t]=a+b; s2[t]=a*a+b*b;
  __syncthreads();
  for(int o=128;o>0;o>>=1){ if(t<o){ s1[t]+=s1[t+o]; s2[t]+=s2[t+o]; } __syncthreads(); }
  if(t==0){
    double m = s1[0]*(1.0/512.0);
    double var = s2[0]*(1.0/512.0) - m*m;
    double sd = sqrt(var + 1e-5);
    meanp[r]=(float)m; stdp[r]=(float)sd; rstdp[r]=(float)(1.0/sd);
    meand[r]=m; rstdd[r]=1.0/sd;
  }
}

// merged embed (blocks [0,NRW)) + gate (blocks [NRW,2NRW)) — both depend only
// on stats; store-bound embed overlaps fp64-VALU gate. Bodies unchanged.
__global__ __launch_bounds__(256) void k_embgate2(
    const float* __restrict__ xT,
    const float* __restrict__ meanp, const float* __restrict__ rstdp,
    const double* __restrict__ meand, const double* __restrict__ rstdd,
    const float* __restrict__ Wval, const float* __restrict__ pe,
    const double* __restrict__ Wvg, const double* __restrict__ peg,
    u16* __restrict__ tglob, int* __restrict__ topip, float2* __restrict__ gatep,
    float* __restrict__ pg, int* __restrict__ pib)
{
  int blk = blockIdx.x, t = threadIdx.x;
  if(blk < NRW){
    // ================= embed =================
    __shared__ __align__(16) float xn[520];
    int r = blk;
    float mean = meanp[r], rstd = rstdp[r];
    float v0 = (xT[(size_t)r*L_ + t]       - mean)*rstd;
    float v1 = (xT[(size_t)r*L_ + 256 + t] - mean)*rstd;
    xn[t] = v0; xn[t+256] = v1;
    if(t==255){
      #pragma unroll
      for(int i=512;i<520;i++) xn[i]=v1;   // edge pad
    }
    int d0 = (t & 63)*2;
    int p0 = t >> 6;
    float2 w[16];
    #pragma unroll
    for(int j=0;j<16;j++) w[j] = *(const float2*)(Wval + j*128 + d0);
    __syncthreads();
    for(int p=p0;p<64;p+=4){
      const float4* xp = (const float4*)(xn + p*8);
      float4 x0=xp[0], x1=xp[1], x2=xp[2], x3=xp[3];
      float xv[16];
      *(float4*)(xv+0)=x0; *(float4*)(xv+4)=x1; *(float4*)(xv+8)=x2; *(float4*)(xv+12)=x3;
      float2 pw = *(const float2*)(pe + p*128 + d0);
      float a0 = pw.x, a1 = pw.y;
      #pragma unroll
      for(int j=0;j<16;j++){ a0 += xv[j]*w[j].x; a1 += xv[j]*w[j].y; }
      u32 packed = (u32)f2bf(a0) | ((u32)f2bf(a1)<<16);
      *(u32*)(tglob + ((size_t)(r*64+p)*128 + d0)) = packed;
    }
    return;
  }
  // ================= gate =================
  {
    __shared__ double xnd[520];
    __shared__ double lgt[64][9];
    int r = blk - NRW;
    double m = meand[r], rs = rstdd[r];
    double v0 = ((double)xT[(size_t)r*L_ + t]       - m)*rs;
    double v1 = ((double)xT[(size_t)r*L_ + 256 + t] - m)*rs;
    xnd[t]=v0; xnd[t+256]=v1;
    if(t==255){
      #pragma unroll
      for(int i=512;i<520;i++) xnd[i]=v1;
    }
    __syncthreads();
    for(int q=t;q<512;q+=256){
      int p = q>>3, e = q&7;
      double acc = peg[q];
      #pragma unroll
      for(int j=0;j<16;j++) acc += xnd[p*8+j]*Wvg[j*8+e];
      lgt[p][e] = acc;
    }
    __syncthreads();
    if(t<64){
      int token = r*64 + t;
      double l0[8];
      #pragma unroll
      for(int e=0;e<8;e++) l0[e]=lgt[t][e];
      double mx=l0[0];
      #pragma unroll
      for(int e=1;e<8;e++) mx = fmax(mx,l0[e]);
      int i1=0; double b1v=l0[0];
      #pragma unroll
      for(int e=1;e<8;e++) if(l0[e]>b1v){b1v=l0[e]; i1=e;}
      int i2=-1; double b2v=-1e300;
      #pragma unroll
      for(int e=0;e<8;e++) if(e!=i1 && l0[e]>b2v){b2v=l0[e]; i2=e;}
      float pr[8]; float sum=0.f;
      #pragma unroll
      for(int e=0;e<8;e++){ pr[e]=__expf((float)(l0[e]-mx)); sum+=pr[e]; }
      float inv = 1.f/sum;
      #pragma unroll
      for(int e=0;e<8;e++) pr[e]*=inv;
      topip[token] = i1 | (i2<<8);
      gatep[token] = make_float2(pr[i1], pr[i2]);
      float lse = (float)mx + __logf(sum);
      #pragma unroll
      for(int e=0;e<8;e++){
        float v = pr[e];
        for(int o=32;o>0;o>>=1) v += __shfl_down(v,o);
        if(t==0) pg[r*12+e] = v;
      }
      {
        float z = lse*lse;
        for(int o=32;o>0;o>>=1) z += __shfl_down(z,o);
        if(t==0) pg[r*12+8] = z;
      }
      #pragma unroll
      for(int e=0;e<8;e++){
        u64 m1 = __ballot(i1==e);
        u64 m2 = __ballot(i2==e);
        if(t==0){
          pib[r*16+e]   = (int)__popcll(m1);
          pib[r*16+8+e] = (int)__popcll(m2);
        }
      }
    }
  }
}

__global__ __launch_bounds__(1024) void k_aux(const float* __restrict__ pg, const int* __restrict__ pib,
                                              int* __restrict__ ci, float* __restrict__ dout){
  __shared__ double sd[1024];
  __shared__ int si[1024];
  __shared__ double totd[9];
  __shared__ int toti[16];
  int t = threadIdx.x;
  double accd[9]; int acci[16];
  #pragma unroll
  for(int c=0;c<9;c++) accd[c]=0.0;
  #pragma unroll
  for(int c=0;c<16;c++) acci[c]=0;
  for(int r=t;r<NRW;r+=1024){
    #pragma unroll
    for(int c=0;c<9;c++) accd[c] += (double)pg[r*12+c];
    #pragma unroll
    for(int c=0;c<16;c++) acci[c] += pib[r*16+c];
  }
  for(int c=0;c<9;c++){
    sd[t]=accd[c]; __syncthreads();
    for(int o=512;o>0;o>>=1){ if(t<o) sd[t]+=sd[t+o]; __syncthreads(); }
    if(t==0) totd[c]=sd[0];
    __syncthreads();
  }
  for(int c=0;c<16;c++){
    si[t]=acci[c]; __syncthreads();
    for(int o=512;o>0;o>>=1){ if(t<o) si[t]+=si[t+o]; __syncthreads(); }
    if(t==0) toti[c]=si[0];
    __syncthreads();
  }
  if(t==0){
    const double invN = 1.0/(double)NTOK;
    double bal = 0.0;
    int es1=0, bs1=0, es2=0, bs2=0;
    for(int e=0;e<8;e++){
      int c1 = toti[e], c2 = toti[8+e];
      bal += (totd[e]*invN) * ((double)(c1+c2) * invN * 0.5);
      ci[32+e]=es1; ci[16+e]=es1; ci[50+e]=bs1;
      ci[41+e]=es2; ci[24+e]=es2; ci[59+e]=bs2;
      es1 += c1; bs1 += (c1+127)>>7;
      es2 += c2; bs2 += (c2+127)>>7;
    }
    ci[40]=es1; ci[58]=bs1;
    ci[49]=es2; ci[67]=bs2;
    dout[493056] = (float)(0.01*8.0*bal + 0.001*(totd[8]*invN));
  }
}

// 1024-thread blocks: 4x fewer global atomics on the 16 hot counters.
__global__ __launch_bounds__(1024) void k_scatter(const int* __restrict__ topip,
    const float2* __restrict__ gatep, int* __restrict__ ci,
    int* __restrict__ btok, float* __restrict__ bgt){
  __shared__ int lc[16]; __shared__ int lb[16];
  int t = threadIdx.x;
  int token = blockIdx.x*1024 + t;
  if(t<16) lc[t]=0;
  __syncthreads();
  int ti = topip[token];
  float2 g = gatep[token];
  int e1 = ti & 255, e2 = (ti>>8)&255;
  int r1 = atomicAdd(&lc[e1],1);
  int r2 = atomicAdd(&lc[8+e2],1);
  __syncthreads();
  if(t<8)            lb[t] = atomicAdd(&ci[16+t],   lc[t]);
  else if(t<16)      lb[t] = atomicAdd(&ci[24+t-8], lc[t]);
  __syncthreads();
  int p1 = lb[e1]+r1, p2 = lb[8+e2]+r2;
  btok[p1] = token;         bgt[p1] = g.x;
  btok[NBUCK+p2] = token;   bgt[NBUCK+p2] = g.y;
}

static __device__ __forceinline__ f32x16 acc1_init(const float* b1l, int hc, int hi){
  f32x16 a;
  const float* bp = b1l + hc*32 + 4*hi;
  #pragma unroll
  for(int qq=0;qq<4;qq++){
    f32x4 b4 = *(const f32x4*)(bp + 8*qq);
    a[4*qq+0]=b4.x; a[4*qq+1]=b4.y; a[4*qq+2]=b4.z; a[4*qq+3]=b4.w;
  }
  return a;
}

static __device__ __forceinline__ void gelu_pack(const f32x16& acc1, bf16x8& fA, bf16x8& fB){
  u32 pk[8];
  #pragma unroll
  for(int i=0;i<8;i++){
    float g0 = gelu_f(acc1[2*i]);
    float g1 = gelu_f(acc1[2*i+1]);
    asm("v_cvt_pk_bf16_f32 %0, %1, %2" : "=v"(pk[i]) : "v"(g0), "v"(g1));
  }
  union { bf16x8 v; u32 w[4]; } uA, uB;
  u32x2 s02 = __builtin_amdgcn_permlane32_swap(pk[0], pk[2], false, false);
  u32x2 s13 = __builtin_amdgcn_permlane32_swap(pk[1], pk[3], false, false);
  u32x2 s46 = __builtin_amdgcn_permlane32_swap(pk[4], pk[6], false, false);
  u32x2 s57 = __builtin_amdgcn_permlane32_swap(pk[5], pk[7], false, false);
  uA.w[0]=s02.x; uA.w[1]=s13.x; uA.w[2]=s02.y; uA.w[3]=s13.y;
  uB.w[0]=s46.x; uB.w[1]=s57.x; uB.w[2]=s46.y; uB.w[3]=s57.y;
  fA = uA.v; fB = uB.v;
}

// fused per-expert FFN v19: v15 + XOR bank-swizzle on W1b/W2b (T2).
// Row stride 136/40 u16 has period-8 bank alias (68*8==0, 20*8==0 mod 32) ->
// lanes {m,m+8,m+16,m+24} 4-way conflict on every ds_read_b128. Fix: swizzle
// byte-in-row c -> c ^ (((row>>3)&3)<<4), applied on BOTH write and read
// (bijective over each row's 16B chunks; same key both sides).
__global__ __launch_bounds__(256,3) void k_expert(
    const u16* __restrict__ tglob,
    const u16* __restrict__ W1T, const u16* __restrict__ W2T,
    const float* __restrict__ b1g, const float* __restrict__ b2g,
    const int* __restrict__ ci,
    const int* __restrict__ btok, const float* __restrict__ bgt,
    u16* __restrict__ outg, u16* __restrict__ outg2)
{
  __shared__ __align__(16) u16 W1b[2][4352];   // 17408 B (rows: 136 u16 = 272 B)
  __shared__ __align__(16) u16 W2b[2][5120];   // 20480 B (rows: 40 u16 = 80 B)
  __shared__ __align__(16) float b1l[512];     //  2048 B

  int bid0 = blockIdx.x, t = threadIdx.x;
  int slot = (bid0 >= NBLK_SLOT) ? 1 : 0;
  int bid  = bid0 - slot*NBLK_SLOT;
  int stB = 32 + slot*9, bsB = 50 + slot*9;
  int boff = slot*NBUCK;
  if(bid >= ci[bsB+8]) return;
  int e = 0;
  #pragma unroll
  for(int k2=1;k2<8;k2++) if(bid >= ci[bsB+k2]) e = k2;
  int row0 = ci[stB+e] + (bid - ci[bsB+e])*128;
  int rend = ci[stB+e+1];

  int wid = t>>6, lane = t&63;
  int m = lane&31, hi = lane>>5;
  int rb = wid*32;                 // wave owns token rows rb..rb+31

  // staging thread roles
  int hr = t>>3, q = t&7;          // W1: row hr (32 rows), two 16B at bytes 32q/32q+16
  int dr = t>>1, q2 = t&1;         // W2: row dr (128 rows), two 16B at bytes 32q2/32q2+16
  // swizzle keys (byte XOR within row)
  int kW1w = ((hr>>3)&3)<<4;       // W1 write key (row hr)
  int kW2w = ((dr>>3)&3)<<4;       // W2 write key (row dr)
  int kRd  = ((m >>3)&3)<<4;       // read key: W1 row m; W2 row (ks&3)*32+m -> same key

  // ---- prologue: W1(0) -> W1b[0]; b1 -> b1l ----
  {
    const u16* s1 = W1T + ((size_t)e*H_ + hr)*128 + q*16;
    uint4 p0 = *(const uint4*)(s1);
    uint4 p1 = *(const uint4*)(s1+8);
    char* d1 = (char*)&W1b[0][0] + hr*272;
    *(uint4*)(d1 + ((32*q)    ^ kW1w)) = p0;
    *(uint4*)(d1 + ((32*q+16) ^ kW1w)) = p1;
    if(t<128){
      float4 bv = *(const float4*)(b1g + e*H_ + t*4);
      *(float4*)(b1l + t*4) = bv;
    }
  }

  // ---- per-lane token, gate, and A-row gather (B-fragment layout) ----
  int posA = row0 + rb + m;
  bool valA = posA < rend;
  int tokA  = valA ? btok[boff+posA] : 0;
  float gt  = valA ? bgt[boff+posA]  : 0.f;
  const u16* arow = tglob + (size_t)tokA*128 + hi*8;
  bf16x8 areg[8];
  #pragma unroll
  for(int ks=0;ks<8;ks++) areg[ks] = *(const bf16x8*)(arow + ks*16);

  // accO init = b2 (O^T layout: lane holds token rb+m, d = nt*32 + 8q + 4hi + r)
  f32x16 accO[4];
  #pragma unroll
  for(int nt=0;nt<4;nt++){
    const float* bp2 = b2g + e*D_ + nt*32 + 4*hi;
    #pragma unroll
    for(int qq=0;qq<4;qq++){
      float4 b4 = *(const float4*)(bp2 + 8*qq);
      accO[nt][4*qq+0]=b4.x; accO[nt][4*qq+1]=b4.y;
      accO[nt][4*qq+2]=b4.z; accO[nt][4*qq+3]=b4.w;
    }
  }
  __syncthreads();   // W1b[0], b1l ready

  bf16x8 fA, fB;
  // ---- iter 0: load W1(1)+W2(0); GEMM1(0); write stages; barrier ----
  {
    const u16* s1 = W1T + ((size_t)e*H_ + 32 + hr)*128 + q*16;
    uint4 l0 = *(const uint4*)(s1), l1 = *(const uint4*)(s1+8);
    const u16* s2 = W2T + ((size_t)e*D_ + dr)*H_ + q2*16;
    uint4 l2 = *(const uint4*)(s2), l3 = *(const uint4*)(s2+8);
    f32x16 acc1 = acc1_init(b1l, 0, hi);
    const char* w1row = (const char*)&W1b[0][0] + m*272;
    __builtin_amdgcn_s_setprio(1);
    #pragma unroll
    for(int ks=0;ks<8;ks++){
      bf16x8 wa = *(const bf16x8*)(w1row + ((ks*32 + hi*16) ^ kRd));
      acc1 = MFMA32(wa, areg[ks], acc1);
    }
    __builtin_amdgcn_s_setprio(0);
    char* d1 = (char*)&W1b[1][0] + hr*272;
    *(uint4*)(d1 + ((32*q)    ^ kW1w)) = l0;
    *(uint4*)(d1 + ((32*q+16) ^ kW1w)) = l1;
    char* d2 = (char*)&W2b[0][0] + dr*80;
    *(uint4*)(d2 + ((32*q2)    ^ kW2w)) = l2;
    *(uint4*)(d2 + ((32*q2+16) ^ kW2w)) = l3;
    gelu_pack(acc1, fA, fB);
    __syncthreads();
  }
  // ---- iters 1..15: load W1(hc+1)+W2(hc); GEMM1(hc) || GEMM2(hc-1); write; barrier
  for(int hc=1; hc<16; hc++){
    uint4 l0, l1;
    if(hc<15){
      const u16* s1 = W1T + ((size_t)e*H_ + (hc+1)*32 + hr)*128 + q*16;
      l0 = *(const uint4*)(s1); l1 = *(const uint4*)(s1+8);
    }
    const u16* s2 = W2T + ((size_t)e*D_ + dr)*H_ + hc*32 + q2*16;
    uint4 l2 = *(const uint4*)(s2), l3 = *(const uint4*)(s2+8);
    f32x16 acc1 = acc1_init(b1l, hc, hi);
    const char* w1row = (const char*)&W1b[hc&1][0] + m*272;
    const char* w2base = (const char*)&W2b[(hc-1)&1][0];
    __builtin_amdgcn_s_setprio(1);
    #pragma unroll
    for(int ks=0;ks<8;ks++){
      bf16x8 wa = *(const bf16x8*)(w1row + ((ks*32 + hi*16) ^ kRd));
      acc1 = MFMA32(wa, areg[ks], acc1);
      bf16x8 a2 = *(const bf16x8*)(w2base + ((ks&3)*32+m)*80
                                   + (((ks>>2)*32 + hi*16) ^ kRd));
      accO[ks&3] = MFMA32(a2, (ks>>2)?fB:fA, accO[ks&3]);
    }
    __builtin_amdgcn_s_setprio(0);
    if(hc<15){
      char* d1 = (char*)&W1b[(hc+1)&1][0] + hr*272;
      *(uint4*)(d1 + ((32*q)    ^ kW1w)) = l0;
      *(uint4*)(d1 + ((32*q+16) ^ kW1w)) = l1;
    }
    char* d2 = (char*)&W2b[hc&1][0] + dr*80;
    *(uint4*)(d2 + ((32*q2)    ^ kW2w)) = l2;
    *(uint4*)(d2 + ((32*q2+16) ^ kW2w)) = l3;
    gelu_pack(acc1, fA, fB);
    __syncthreads();
  }
  // ---- tail: GEMM2(15) from W2b[1] ----
  {
    const char* w2base = (const char*)&W2b[1][0];
    __builtin_amdgcn_s_setprio(1);
    #pragma unroll
    for(int ks=0;ks<8;ks++){
      bf16x8 a2 = *(const bf16x8*)(w2base + ((ks&3)*32+m)*80
                                   + (((ks>>2)*32 + hi*16) ^ kRd));
      accO[ks&3] = MFMA32(a2, (ks>>2)?fB:fA, accO[ks&3]);
    }
    __builtin_amdgcn_s_setprio(0);
  }

  // ---- epilogue: per-lane gate-scale + pack + plain 8B stores (no RMW).
  if(valA){
    u16* obase = (slot ? outg2 : outg) + (size_t)tokA*128 + 4*hi;
    #pragma unroll
    for(int nt=0;nt<4;nt++){
      #pragma unroll
      for(int qq=0;qq<4;qq++){
        float v0 = accO[nt][4*qq+0]*gt;
        float v1 = accO[nt][4*qq+1]*gt;
        float v2 = accO[nt][4*qq+2]*gt;
        float v3 = accO[nt][4*qq+3]*gt;
        u32 w0, w1;
        asm("v_cvt_pk_bf16_f32 %0, %1, %2" : "=v"(w0) : "v"(v0), "v"(v1));
        asm("v_cvt_pk_bf16_f32 %0, %1, %2" : "=v"(w1) : "v"(v2), "v"(v3));
        u32x2 nv; nv.x = w0; nv.y = w1;
        *(u32x2*)(obase + nt*32 + 8*qq) = nv;
      }
    }
  }
}

// head GEMM: A = outg + outg2 (summed bf16 rows), B = WhT2[o][k'].
// wave owns 16 rows, 8-way K-split, no LDS, plain stores to dec8.
__global__ __launch_bounds__(256) void k_head(const u16* __restrict__ Aout,
    const u16* __restrict__ Aout2,
    const u16* __restrict__ WhT2, float* __restrict__ dec8){
  int bid = blockIdx.x;                 // 81 mtiles x 8 ksegs
  int mb = bid>>3, kseg = bid&7;
  int t = threadIdx.x, wid = t>>6, lane = t&63;
  int quad = lane>>4, li = lane&15;
  int r0 = mb*64 + wid*16;
  int rowA = r0 + li; if(rowA >= NRW) rowA = NRW-1;
  size_t abase = (size_t)rowA*DP_ + kseg*1024 + quad*8;
  const u16* aptr  = Aout  + abase;
  const u16* aptr2 = Aout2 + abase;
  const u16* bptr = WhT2 + (size_t)li*DP_  + kseg*1024 + quad*8;
  f32x4 acc[6];
  #pragma unroll
  for(int j=0;j<6;j++) acc[j]=(f32x4){0,0,0,0};
  #pragma unroll 4
  for(int ks=0;ks<32;ks++){
    uint4 va = *(const uint4*)(aptr  + ks*32);
    uint4 vb = *(const uint4*)(aptr2 + ks*32);
    union { uint4 u; bf16x8 v; } vs;
    vs.u.x = bfadd2(va.x, vb.x);
    vs.u.y = bfadd2(va.y, vb.y);
    vs.u.z = bfadd2(va.z, vb.z);
    vs.u.w = bfadd2(va.w, vb.w);
    bf16x8 af = vs.v;
    #pragma unroll
    for(int nt=0;nt<6;nt++){
      bf16x8 bw = *(const bf16x8*)(bptr + (size_t)nt*16*DP_ + ks*32);
      acc[nt] = MFMA16(af, bw, acc[nt]);
    }
  }
  float* dst = dec8 + (size_t)kseg*NRW*96;
  #pragma unroll
  for(int nt=0;nt<6;nt++)
    #pragma unroll
    for(int rg=0;rg<4;rg++){
      int mm = r0 + quad*4 + rg;
      if(mm < NRW) dst[(size_t)mm*96 + nt*16 + li] = acc[nt][rg];
    }
}

// sum 8 k-segments + transpose + bias + denorm
__global__ void k_final(const float* __restrict__ dec8, const float* __restrict__ bhead,
    const float* __restrict__ stdp, const float* __restrict__ meanp, float* __restrict__ outp){
  __shared__ float s[64*97];
  int b = blockIdx.y, v0 = blockIdx.x*64;
  int t = threadIdx.x;
  for(int i=t;i<6144;i+=256){
    int vi = i/96, o = i - vi*96;
    int v = v0+vi;
    float acc = 0.f;
    if(v<NV_){
      size_t base = (size_t)(b*NV_+v)*96 + o;
      #pragma unroll
      for(int ks=0;ks<8;ks++) acc += dec8[(size_t)ks*NRW*96 + base];
    }
    s[vi*97+o] = acc;
  }
  __syncthreads();
  for(int i=t;i<6144;i+=256){
    int o = i>>6, vi = i&63;
    int v = v0+vi;
    if(v<NV_){
      int r = b*NV_+v;
      outp[((size_t)b*96 + o)*NV_ + v] = (s[vi*97+o] + bhead[o])*stdp[r] + meanp[r];
    }
  }
}

// ============ launcher ============
extern "C" void kernel_launch(void* const* d_in, const int* in_sizes, int n_in,
                              void* d_out, int out_size, void* d_ws, size_t ws_size,
                              hipStream_t stream){
  const float* x_enc = (const float*)d_in[0];
  const float* W_val = (const float*)d_in[4];
  const float* W_g   = (const float*)d_in[5];
  const float* W1    = (const float*)d_in[6];
  const float* b1    = (const float*)d_in[7];
  const float* W2    = (const float*)d_in[8];
  const float* b2    = (const float*)d_in[9];
  const float* W_head= (const float*)d_in[10];
  const float* b_head= (const float*)d_in[11];
  float* outp = (float*)d_out;
  char* ws = (char*)d_ws;

  float* meanp = (float*)(ws+OFF_MEAN);
  float* rstdp = (float*)(ws+OFF_RSTD);
  float* stdp  = (float*)(ws+OFF_STD);
  float* xT    = (float*)(ws+OFF_XT);
  float* pe    = (float*)(ws+OFF_PE);
  u16*   W1T   = (u16*)(ws+OFF_W1T);
  u16*   W2T   = (u16*)(ws+OFF_W2T);
  u16*   WhT2  = (u16*)(ws+OFF_WHT);
  u16*   tglob = (u16*)(ws+OFF_T);
  float* dec8  = (float*)(ws+OFF_T);    // aliases tglob (dead after expert gather)
  int*   topip = (int*)(ws+OFF_TOPI);
  float2* gatep= (float2*)(ws+OFF_GATE);
  int*   ci    = (int*)(ws+OFF_CNTR+128);
  int*   btok  = (int*)(ws+OFF_BTOK);
  float* bgt   = (float*)(ws+OFF_BGT);
  u16*   outg  = (u16*)(ws+OFF_OUT);
  u16*   outg2 = (u16*)(ws+OFF_OUT2);   // transients xT/pe/topip/gatep/pg/pib alias this
  double* meand= (double*)(ws+OFF_MEAND);
  double* rstdd= (double*)(ws+OFF_RSTDD);
  double* Wvg  = (double*)(ws+OFF_WVG);
  double* peg  = (double*)(ws+OFF_PEG);
  float* pg    = (float*)(ws+OFF_PG);
  int*   pib   = (int*)(ws+OFF_PI);

  k_xtprep<<<4609, dim3(32,8), 0, stream>>>(x_enc, xT, W_val, W_g, W1, W2, W_head,
                                            pe, Wvg, peg, W1T, W2T, WhT2);
  k_stats<<<NRW, 256, 0, stream>>>(xT, meanp, rstdp, stdp, meand, rstdd);
  k_embgate2<<<2*NRW, 256, 0, stream>>>(xT, meanp, rstdp, meand, rstdd,
                                        W_val, pe, Wvg, peg,
                                        tglob, topip, gatep, pg, pib);
  k_aux<<<1, 1024, 0, stream>>>(pg, pib, ci, outp);
  k_scatter<<<NTOK/1024, 1024, 0, stream>>>(topip, gatep, ci, btok, bgt);
  k_expert<<<2*NBLK_SLOT, 256, 0, stream>>>(tglob, W1T, W2T, b1, b2, ci, btok, bgt,
                                            outg, outg2);
  k_head<<<648, 256, 0, stream>>>(outg, outg2, WhT2, dec8);
  k_final<<<dim3(6,B_), 256, 0, stream>>>(dec8, b_head, stdp, meanp, outp);
}

// Round 13
// 564.279 us; speedup vs baseline: 1.0389x; 1.0389x over previous
//
#include <hip/hip_runtime.h>
#include <hip/hip_bf16.h>

typedef unsigned short u16;
typedef unsigned int   u32;
typedef unsigned long long u64;
typedef __attribute__((ext_vector_type(8))) short bf16x8;
typedef __attribute__((ext_vector_type(4))) float f32x4;
typedef __attribute__((ext_vector_type(16))) float f32x16;
typedef __attribute__((ext_vector_type(2))) unsigned int u32x2;

#define MFMA16(a,b,c) __builtin_amdgcn_mfma_f32_16x16x32_bf16(a,b,c,0,0,0)
#define MFMA32(a,b,c) __builtin_amdgcn_mfma_f32_32x32x16_bf16(a,b,c,0,0,0)

// ---- problem dims ----
#define NV_   321
#define B_    16
#define L_    512
#define D_    128
#define P_    64
#define E_    8
#define H_    512
#define NRW   5136        // B*NV
#define NTOK  328704      // NRW*P
#define DP_   8192        // D*P
#define NBUCK 329728      // NTOK + 8*128 padding
#define NBLK_SLOT 2576    // max expert blocks per slot

static __device__ __forceinline__ u16 f2bf(float f){
  __hip_bfloat16 h = __float2bfloat16(f);
  return *reinterpret_cast<u16*>(&h);
}

static __device__ __forceinline__ u32 bfadd2(u32 a, u32 b){
  float lo = __uint_as_float(a<<16)           + __uint_as_float(b<<16);
  float hi = __uint_as_float(a&0xffff0000u)   + __uint_as_float(b&0xffff0000u);
  return (u32)f2bf(lo) | ((u32)f2bf(hi)<<16);
}

// sigma-form tanh-GELU: x*sigma(1.5958x(1+0.044715x^2)); exp2 maps to v_exp_f32
static __device__ __forceinline__ float gelu_f(float x){
  float x2 = x*x;
  float p  = __builtin_fmaf(-0.1029433f, x2, -2.3022083f);
  float a  = x*p;
  float en = exp2f(a);
  float r  = __builtin_amdgcn_rcpf(1.0f + en);
  return x*r;
}

// ============ workspace layout (bytes) — end ~249.4 MiB (budget 256 MiB) ============
// Permanent (live across expert dispatch):
static constexpr size_t alup(size_t x){ return (x + 255) & ~(size_t)255; }
static constexpr size_t OFF_MEAN = 0;
static constexpr size_t OFF_RSTD = OFF_MEAN + alup((size_t)NRW*4);
static constexpr size_t OFF_STD  = OFF_RSTD + alup((size_t)NRW*4);
static constexpr size_t OFF_MEAND= OFF_STD  + alup((size_t)NRW*4);
static constexpr size_t OFF_RSTDD= OFF_MEAND+ alup((size_t)NRW*8);
static constexpr size_t OFF_WVG  = OFF_RSTDD+ alup((size_t)NRW*8);
static constexpr size_t OFF_PEG  = OFF_WVG  + alup((size_t)16*8*8);
static constexpr size_t OFF_W1T  = OFF_PEG  + alup((size_t)P_*E_*8);
static constexpr size_t OFF_W2T  = OFF_W1T  + alup((size_t)E_*H_*D_*2);
static constexpr size_t OFF_WHT  = OFF_W2T  + alup((size_t)E_*D_*H_*2);
static constexpr size_t OFF_T    = OFF_WHT  + alup((size_t)96*DP_*2);      // tokens bf16; later ALIASED as dec8
static constexpr size_t OFF_CNTR = OFF_T    + alup((size_t)NTOK*D_*2);
static constexpr size_t OFF_BTOK = OFF_CNTR + alup((size_t)1024);
static constexpr size_t OFF_BGT  = OFF_BTOK + alup((size_t)2*NBUCK*4);
static constexpr size_t OFF_OUT  = OFF_BGT  + alup((size_t)2*NBUCK*4);     // slot-0 outputs bf16 [token][d]
static constexpr size_t OFF_OUT2 = OFF_OUT  + alup((size_t)NTOK*D_*2);     // slot-1 outputs bf16 [token][d]
// Transients (dead before first expert write) — ALIAS the OUT2 region:
static constexpr size_t OFF_XT   = OFF_OUT2;
static constexpr size_t OFF_PE   = OFF_XT   + alup((size_t)NRW*L_*4);
static constexpr size_t OFF_TOPI = OFF_PE   + alup((size_t)P_*D_*4);
static constexpr size_t OFF_GATE = OFF_TOPI + alup((size_t)NTOK*4);
static constexpr size_t OFF_PG   = OFF_GATE + alup((size_t)NTOK*8);
static constexpr size_t OFF_PI   = OFF_PG   + alup((size_t)NRW*12*4);
static_assert(OFF_PI + (size_t)NRW*16*4 <= OFF_OUT2 + (size_t)NTOK*D_*2,
              "transients must fit inside outg2 alias region");

// ci ints at OFF_CNTR+128: [16..23]=cur1 [24..31]=cur2
// [32..40]=start1 [41..49]=start2 [50..58]=bstart1 [59..67]=bstart2
// NOTE: no memset needed — k_aux fully writes [16..67] before any reader.

// ============ kernels ============

// merged x-transpose (blocks [0,2816)) + weight-prep (blocks [2816,4609)) —
// independent work, same 256-thread (32,8) shape; overlap in one dispatch.
__global__ void k_xtprep(const float* __restrict__ x, float* __restrict__ xT,
                         const float* __restrict__ Wval, const float* __restrict__ Wg,
                         const float* __restrict__ W1, const float* __restrict__ W2,
                         const float* __restrict__ Wh,
                         float* __restrict__ pef, double* __restrict__ Wvg,
                         double* __restrict__ peg,
                         u16* __restrict__ W1T, u16* __restrict__ W2T,
                         u16* __restrict__ WhT2){
  __shared__ float tile[32][33];
  int blk = blockIdx.x;
  int tx = threadIdx.x, ty = threadIdx.y;
  int t = ty*32 + tx;
  if(blk < 2816){
    // ---- x transpose: decode (bx,by,bz) from former dim3(11,16,16) grid ----
    int bz = blk/176, rem = blk - bz*176;
    int by = rem/11,  bx  = rem - by*11;
    int b = bz;
    int v0 = bx*32, l0 = by*32;
    for(int i=ty;i<32;i+=8){
      int l = l0+i, v = v0+tx;
      tile[i][tx] = (v<NV_) ? x[((size_t)b*L_ + l)*NV_ + v] : 0.f;
    }
    __syncthreads();
    for(int i=ty;i<32;i+=8){
      int v = v0+i, l = l0+tx;
      if(v<NV_) xT[((size_t)(b*NV_+v))*L_ + l] = tile[tx][i];
    }
    return;
  }
  int bb = blk - 2816;   // weight-prep block id (0..1792)
  if(bb == 0){
    for(int i=t;i<8192;i+=256){
      int p = i>>7, d = i&127, k = d>>1;
      double div = exp(-(double)(2*k) * (9.210340371976184 /128.0)); // ln(10000)/128
      double ang = (double)p * div;
      double v = (d&1) ? cos(ang) : sin(ang);
      pef[i] = (float)v;
    }
    __syncthreads();
    if(t<128){
      int j = t>>3, e = t&7;
      double acc = 0.0;
      for(int d=0;d<128;d++) acc += (double)Wval[j*128+d] * (double)Wg[d*8+e];
      Wvg[t] = acc;
    }
    for(int q=t;q<512;q+=256){
      int p = q>>3, e = q&7;
      double acc = 0.0;
      for(int d=0;d<128;d++) acc += (double)pef[p*128+d] * (double)Wg[d*8+e];
      peg[q] = acc;
    }
    return;
  }
  if(bb < 1025){
    // W1: R=128,C=512, tiles (16 x 4); W2: R=512,C=128, tiles (4 x 16)
    bool isW1 = (bb < 513);
    int rem = isW1 ? (bb-1) : (bb-513);
    int e = rem >> 6, r6 = rem & 63;
    int R = isW1 ? 128 : 512, C = isW1 ? 512 : 128;
    int c0 = (isW1 ? (r6 & 15) : (r6 & 3))*32;
    int r0 = (isW1 ? (r6 >> 4) : (r6 >> 2))*32;
    const float* src = (isW1 ? W1 : W2) + (size_t)e*R*C;
    u16* dst = (isW1 ? W1T : W2T) + (size_t)e*R*C;
    for(int i=ty;i<32;i+=8){
      int r=r0+i, c=c0+tx;
      tile[i][tx] = (r<R && c<C) ? src[(size_t)r*C+c] : 0.f;
    }
    __syncthreads();
    for(int i=ty;i<32;i+=8){
      int c=c0+i, r=r0+tx;
      if(c<C && r<R) dst[(size_t)c*R + r] = f2bf(tile[tx][i]);
    }
    return;
  }
  {
    int rem = bb - 1025;
    int p = rem / 12, rr = rem - p*12;
    int d0 = (rr & 3)*32, o0 = (rr >> 2)*32;
    for(int i=ty;i<32;i+=8){
      int r = (d0+i)*64 + p;
      tile[i][tx] = Wh[(size_t)r*96 + o0 + tx];
    }
    __syncthreads();
    for(int i=ty;i<32;i+=8){
      int o = o0+i;
      WhT2[(size_t)o*DP_ + p*128 + d0 + tx] = f2bf(tile[tx][i]);
    }
  }
}

__global__ void k_stats(const float* __restrict__ xT, float* meanp, float* rstdp, float* stdp,
                        double* meand, double* rstdd){
  __shared__ double s1[256], s2[256];
  int r = blockIdx.x, t = threadIdx.x;
  double a = (double)xT[(size_t)r*L_ + t], b = (double)xT[(size_t)r*L_ + 256 + t];
  s1[t]=a+b; s2[t]=a*a+b*b;
  __syncthreads();
  for(int o=128;o>0;o>>=1){ if(t<o){ s1[t]+=s1[t+o]; s2[t]+=s2[t+o]; } __syncthreads(); }
  if(t==0){
    double m = s1[0]*(1.0/512.0);
    double var = s2[0]*(1.0/512.0) - m*m;
    double sd = sqrt(var + 1e-5);
    meanp[r]=(float)m; stdp[r]=(float)sd; rstdp[r]=(float)(1.0/sd);
    meand[r]=m; rstdd[r]=1.0/sd;
  }
}

// merged embed (blocks [0,NRW)) + gate (blocks [NRW,2NRW)) — both depend only
// on stats; store-bound embed overlaps fp64-VALU gate. Bodies unchanged.
__global__ __launch_bounds__(256) void k_embgate2(
    const float* __restrict__ xT,
    const float* __restrict__ meanp, const float* __restrict__ rstdp,
    const double* __restrict__ meand, const double* __restrict__ rstdd,
    const float* __restrict__ Wval, const float* __restrict__ pe,
    const double* __restrict__ Wvg, const double* __restrict__ peg,
    u16* __restrict__ tglob, int* __restrict__ topip, float2* __restrict__ gatep,
    float* __restrict__ pg, int* __restrict__ pib)
{
  int blk = blockIdx.x, t = threadIdx.x;
  if(blk < NRW){
    // ================= embed =================
    __shared__ __align__(16) float xn[520];
    int r = blk;
    float mean = meanp[r], rstd = rstdp[r];
    float v0 = (xT[(size_t)r*L_ + t]       - mean)*rstd;
    float v1 = (xT[(size_t)r*L_ + 256 + t] - mean)*rstd;
    xn[t] = v0; xn[t+256] = v1;
    if(t==255){
      #pragma unroll
      for(int i=512;i<520;i++) xn[i]=v1;   // edge pad
    }
    int d0 = (t & 63)*2;
    int p0 = t >> 6;
    float2 w[16];
    #pragma unroll
    for(int j=0;j<16;j++) w[j] = *(const float2*)(Wval + j*128 + d0);
    __syncthreads();
    for(int p=p0;p<64;p+=4){
      const float4* xp = (const float4*)(xn + p*8);
      float4 x0=xp[0], x1=xp[1], x2=xp[2], x3=xp[3];
      float xv[16];
      *(float4*)(xv+0)=x0; *(float4*)(xv+4)=x1; *(float4*)(xv+8)=x2; *(float4*)(xv+12)=x3;
      float2 pw = *(const float2*)(pe + p*128 + d0);
      float a0 = pw.x, a1 = pw.y;
      #pragma unroll
      for(int j=0;j<16;j++){ a0 += xv[j]*w[j].x; a1 += xv[j]*w[j].y; }
      u32 packed = (u32)f2bf(a0) | ((u32)f2bf(a1)<<16);
      *(u32*)(tglob + ((size_t)(r*64+p)*128 + d0)) = packed;
    }
    return;
  }
  // ================= gate =================
  {
    __shared__ double xnd[520];
    __shared__ double lgt[64][9];
    int r = blk - NRW;
    double m = meand[r], rs = rstdd[r];
    double v0 = ((double)xT[(size_t)r*L_ + t]       - m)*rs;
    double v1 = ((double)xT[(size_t)r*L_ + 256 + t] - m)*rs;
    xnd[t]=v0; xnd[t+256]=v1;
    if(t==255){
      #pragma unroll
      for(int i=512;i<520;i++) xnd[i]=v1;
    }
    __syncthreads();
    for(int q=t;q<512;q+=256){
      int p = q>>3, e = q&7;
      double acc = peg[q];
      #pragma unroll
      for(int j=0;j<16;j++) acc += xnd[p*8+j]*Wvg[j*8+e];
      lgt[p][e] = acc;
    }
    __syncthreads();
    if(t<64){
      int token = r*64 + t;
      double l0[8];
      #pragma unroll
      for(int e=0;e<8;e++) l0[e]=lgt[t][e];
      double mx=l0[0];
      #pragma unroll
      for(int e=1;e<8;e++) mx = fmax(mx,l0[e]);
      int i1=0; double b1v=l0[0];
      #pragma unroll
      for(int e=1;e<8;e++) if(l0[e]>b1v){b1v=l0[e]; i1=e;}
      int i2=-1; double b2v=-1e300;
      #pragma unroll
      for(int e=0;e<8;e++) if(e!=i1 && l0[e]>b2v){b2v=l0[e]; i2=e;}
      float pr[8]; float sum=0.f;
      #pragma unroll
      for(int e=0;e<8;e++){ pr[e]=__expf((float)(l0[e]-mx)); sum+=pr[e]; }
      float inv = 1.f/sum;
      #pragma unroll
      for(int e=0;e<8;e++) pr[e]*=inv;
      topip[token] = i1 | (i2<<8);
      gatep[token] = make_float2(pr[i1], pr[i2]);
      float lse = (float)mx + __logf(sum);
      #pragma unroll
      for(int e=0;e<8;e++){
        float v = pr[e];
        for(int o=32;o>0;o>>=1) v += __shfl_down(v,o);
        if(t==0) pg[r*12+e] = v;
      }
      {
        float z = lse*lse;
        for(int o=32;o>0;o>>=1) z += __shfl_down(z,o);
        if(t==0) pg[r*12+8] = z;
      }
      #pragma unroll
      for(int e=0;e<8;e++){
        u64 m1 = __ballot(i1==e);
        u64 m2 = __ballot(i2==e);
        if(t==0){
          pib[r*16+e]   = (int)__popcll(m1);
          pib[r*16+8+e] = (int)__popcll(m2);
        }
      }
    }
  }
}

__global__ __launch_bounds__(1024) void k_aux(const float* __restrict__ pg, const int* __restrict__ pib,
                                              int* __restrict__ ci, float* __restrict__ dout){
  __shared__ double sd[1024];
  __shared__ int si[1024];
  __shared__ double totd[9];
  __shared__ int toti[16];
  int t = threadIdx.x;
  double accd[9]; int acci[16];
  #pragma unroll
  for(int c=0;c<9;c++) accd[c]=0.0;
  #pragma unroll
  for(int c=0;c<16;c++) acci[c]=0;
  for(int r=t;r<NRW;r+=1024){
    #pragma unroll
    for(int c=0;c<9;c++) accd[c] += (double)pg[r*12+c];
    #pragma unroll
    for(int c=0;c<16;c++) acci[c] += pib[r*16+c];
  }
  for(int c=0;c<9;c++){
    sd[t]=accd[c]; __syncthreads();
    for(int o=512;o>0;o>>=1){ if(t<o) sd[t]+=sd[t+o]; __syncthreads(); }
    if(t==0) totd[c]=sd[0];
    __syncthreads();
  }
  for(int c=0;c<16;c++){
    si[t]=acci[c]; __syncthreads();
    for(int o=512;o>0;o>>=1){ if(t<o) si[t]+=si[t+o]; __syncthreads(); }
    if(t==0) toti[c]=si[0];
    __syncthreads();
  }
  if(t==0){
    const double invN = 1.0/(double)NTOK;
    double bal = 0.0;
    int es1=0, bs1=0, es2=0, bs2=0;
    for(int e=0;e<8;e++){
      int c1 = toti[e], c2 = toti[8+e];
      bal += (totd[e]*invN) * ((double)(c1+c2) * invN * 0.5);
      ci[32+e]=es1; ci[16+e]=es1; ci[50+e]=bs1;
      ci[41+e]=es2; ci[24+e]=es2; ci[59+e]=bs2;
      es1 += c1; bs1 += (c1+127)>>7;
      es2 += c2; bs2 += (c2+127)>>7;
    }
    ci[40]=es1; ci[58]=bs1;
    ci[49]=es2; ci[67]=bs2;
    dout[493056] = (float)(0.01*8.0*bal + 0.001*(totd[8]*invN));
  }
}

// 1024-thread blocks: 4x fewer global atomics on the 16 hot counters.
__global__ __launch_bounds__(1024) void k_scatter(const int* __restrict__ topip,
    const float2* __restrict__ gatep, int* __restrict__ ci,
    int* __restrict__ btok, float* __restrict__ bgt){
  __shared__ int lc[16]; __shared__ int lb[16];
  int t = threadIdx.x;
  int token = blockIdx.x*1024 + t;
  if(t<16) lc[t]=0;
  __syncthreads();
  int ti = topip[token];
  float2 g = gatep[token];
  int e1 = ti & 255, e2 = (ti>>8)&255;
  int r1 = atomicAdd(&lc[e1],1);
  int r2 = atomicAdd(&lc[8+e2],1);
  __syncthreads();
  if(t<8)            lb[t] = atomicAdd(&ci[16+t],   lc[t]);
  else if(t<16)      lb[t] = atomicAdd(&ci[24+t-8], lc[t]);
  __syncthreads();
  int p1 = lb[e1]+r1, p2 = lb[8+e2]+r2;
  btok[p1] = token;         bgt[p1] = g.x;
  btok[NBUCK+p2] = token;   bgt[NBUCK+p2] = g.y;
}

static __device__ __forceinline__ f32x16 acc1_init(const float* b1l, int hc, int hi){
  f32x16 a;
  const float* bp = b1l + hc*32 + 4*hi;
  #pragma unroll
  for(int qq=0;qq<4;qq++){
    f32x4 b4 = *(const f32x4*)(bp + 8*qq);
    a[4*qq+0]=b4.x; a[4*qq+1]=b4.y; a[4*qq+2]=b4.z; a[4*qq+3]=b4.w;
  }
  return a;
}

static __device__ __forceinline__ void gelu_pack(const f32x16& acc1, bf16x8& fA, bf16x8& fB){
  u32 pk[8];
  #pragma unroll
  for(int i=0;i<8;i++){
    float g0 = gelu_f(acc1[2*i]);
    float g1 = gelu_f(acc1[2*i+1]);
    asm("v_cvt_pk_bf16_f32 %0, %1, %2" : "=v"(pk[i]) : "v"(g0), "v"(g1));
  }
  union { bf16x8 v; u32 w[4]; } uA, uB;
  u32x2 s02 = __builtin_amdgcn_permlane32_swap(pk[0], pk[2], false, false);
  u32x2 s13 = __builtin_amdgcn_permlane32_swap(pk[1], pk[3], false, false);
  u32x2 s46 = __builtin_amdgcn_permlane32_swap(pk[4], pk[6], false, false);
  u32x2 s57 = __builtin_amdgcn_permlane32_swap(pk[5], pk[7], false, false);
  uA.w[0]=s02.x; uA.w[1]=s13.x; uA.w[2]=s02.y; uA.w[3]=s13.y;
  uB.w[0]=s46.x; uB.w[1]=s57.x; uB.w[2]=s46.y; uB.w[3]=s57.y;
  fA = uA.v; fB = uB.v;
}

// fused per-expert FFN (v15/v18 form — best measured): reg-staged weights,
// skewed pipeline (GEMM1(hc) || GEMM2(hc-1)), b1 in LDS, one barrier per iter,
// BOTH slots in one dispatch. LDS b128 reads are at the 8-dword/bank floor —
// do not "fix" the bank-conflict counter (R12 lesson).
__global__ __launch_bounds__(256,3) void k_expert(
    const u16* __restrict__ tglob,
    const u16* __restrict__ W1T, const u16* __restrict__ W2T,
    const float* __restrict__ b1g, const float* __restrict__ b2g,
    const int* __restrict__ ci,
    const int* __restrict__ btok, const float* __restrict__ bgt,
    u16* __restrict__ outg, u16* __restrict__ outg2)
{
  __shared__ __align__(16) u16 W1b[2][4352];   // 17408 B (rows: 136 u16, cols 128 used)
  __shared__ __align__(16) u16 W2b[2][5120];   // 20480 B (rows: 40 u16, cols 32 used)
  __shared__ __align__(16) float b1l[512];     //  2048 B

  int bid0 = blockIdx.x, t = threadIdx.x;
  int slot = (bid0 >= NBLK_SLOT) ? 1 : 0;
  int bid  = bid0 - slot*NBLK_SLOT;
  int stB = 32 + slot*9, bsB = 50 + slot*9;
  int boff = slot*NBUCK;
  if(bid >= ci[bsB+8]) return;
  int e = 0;
  #pragma unroll
  for(int k2=1;k2<8;k2++) if(bid >= ci[bsB+k2]) e = k2;
  int row0 = ci[stB+e] + (bid - ci[bsB+e])*128;
  int rend = ci[stB+e+1];

  int wid = t>>6, lane = t&63;
  int m = lane&31, hi = lane>>5;
  int rb = wid*32;                 // wave owns token rows rb..rb+31

  // staging thread roles
  int hr = t>>3, q = t&7;          // W1: row hr (32 rows), 16 u16 at q*16
  int dr = t>>1, q2 = t&1;         // W2: row dr (128 rows), 16 u16 at q2*16

  // ---- prologue: W1(0) -> W1b[0]; b1 -> b1l ----
  {
    const u16* s1 = W1T + ((size_t)e*H_ + hr)*128 + q*16;
    uint4 p0 = *(const uint4*)(s1);
    uint4 p1 = *(const uint4*)(s1+8);
    u16* d1 = &W1b[0][hr*136 + q*16];
    *(uint4*)(d1)   = p0;
    *(uint4*)(d1+8) = p1;
    if(t<128){
      float4 bv = *(const float4*)(b1g + e*H_ + t*4);
      *(float4*)(b1l + t*4) = bv;
    }
  }

  // ---- per-lane token, gate, and A-row gather (B-fragment layout) ----
  int posA = row0 + rb + m;
  bool valA = posA < rend;
  int tokA  = valA ? btok[boff+posA] : 0;
  float gt  = valA ? bgt[boff+posA]  : 0.f;
  const u16* arow = tglob + (size_t)tokA*128 + hi*8;
  bf16x8 areg[8];
  #pragma unroll
  for(int ks=0;ks<8;ks++) areg[ks] = *(const bf16x8*)(arow + ks*16);

  // accO init = b2 (O^T layout: lane holds token rb+m, d = nt*32 + 8q + 4hi + r)
  f32x16 accO[4];
  #pragma unroll
  for(int nt=0;nt<4;nt++){
    const float* bp2 = b2g + e*D_ + nt*32 + 4*hi;
    #pragma unroll
    for(int qq=0;qq<4;qq++){
      float4 b4 = *(const float4*)(bp2 + 8*qq);
      accO[nt][4*qq+0]=b4.x; accO[nt][4*qq+1]=b4.y;
      accO[nt][4*qq+2]=b4.z; accO[nt][4*qq+3]=b4.w;
    }
  }
  __syncthreads();   // W1b[0], b1l ready

  bf16x8 fA, fB;
  // ---- iter 0: load W1(1)+W2(0); GEMM1(0); write stages; barrier ----
  {
    const u16* s1 = W1T + ((size_t)e*H_ + 32 + hr)*128 + q*16;
    uint4 l0 = *(const uint4*)(s1), l1 = *(const uint4*)(s1+8);
    const u16* s2 = W2T + ((size_t)e*D_ + dr)*H_ + q2*16;
    uint4 l2 = *(const uint4*)(s2), l3 = *(const uint4*)(s2+8);
    f32x16 acc1 = acc1_init(b1l, 0, hi);
    __builtin_amdgcn_s_setprio(1);
    #pragma unroll
    for(int ks=0;ks<8;ks++){
      bf16x8 wa = *(const bf16x8*)(&W1b[0][0] + m*136 + ks*16 + hi*8);
      acc1 = MFMA32(wa, areg[ks], acc1);
    }
    __builtin_amdgcn_s_setprio(0);
    u16* d1 = &W1b[1][hr*136 + q*16];
    *(uint4*)(d1)   = l0; *(uint4*)(d1+8) = l1;
    u16* d2 = &W2b[0][dr*40 + q2*16];
    *(uint4*)(d2)   = l2; *(uint4*)(d2+8) = l3;
    gelu_pack(acc1, fA, fB);
    __syncthreads();
  }
  // ---- iters 1..15: load W1(hc+1)+W2(hc); GEMM1(hc) || GEMM2(hc-1); write; barrier
  for(int hc=1; hc<16; hc++){
    uint4 l0, l1;
    if(hc<15){
      const u16* s1 = W1T + ((size_t)e*H_ + (hc+1)*32 + hr)*128 + q*16;
      l0 = *(const uint4*)(s1); l1 = *(const uint4*)(s1+8);
    }
    const u16* s2 = W2T + ((size_t)e*D_ + dr)*H_ + hc*32 + q2*16;
    uint4 l2 = *(const uint4*)(s2), l3 = *(const uint4*)(s2+8);
    f32x16 acc1 = acc1_init(b1l, hc, hi);
    const u16* W1c = &W1b[hc&1][0];
    const u16* W2p = &W2b[(hc-1)&1][0];
    __builtin_amdgcn_s_setprio(1);
    #pragma unroll
    for(int ks=0;ks<8;ks++){
      bf16x8 wa = *(const bf16x8*)(W1c + m*136 + ks*16 + hi*8);
      acc1 = MFMA32(wa, areg[ks], acc1);
      bf16x8 a2 = *(const bf16x8*)(W2p + ((ks&3)*32+m)*40 + (ks>>2)*16 + hi*8);
      accO[ks&3] = MFMA32(a2, (ks>>2)?fB:fA, accO[ks&3]);
    }
    __builtin_amdgcn_s_setprio(0);
    if(hc<15){
      u16* d1 = &W1b[(hc+1)&1][hr*136 + q*16];
      *(uint4*)(d1)   = l0; *(uint4*)(d1+8) = l1;
    }
    u16* d2 = &W2b[hc&1][dr*40 + q2*16];
    *(uint4*)(d2)   = l2; *(uint4*)(d2+8) = l3;
    gelu_pack(acc1, fA, fB);
    __syncthreads();
  }
  // ---- tail: GEMM2(15) from W2b[1] ----
  {
    const u16* W2p = &W2b[1][0];
    __builtin_amdgcn_s_setprio(1);
    #pragma unroll
    for(int ks=0;ks<8;ks++){
      bf16x8 a2 = *(const bf16x8*)(W2p + ((ks&3)*32+m)*40 + (ks>>2)*16 + hi*8);
      accO[ks&3] = MFMA32(a2, (ks>>2)?fB:fA, accO[ks&3]);
    }
    __builtin_amdgcn_s_setprio(0);
  }

  // ---- epilogue: per-lane gate-scale + pack + plain 8B stores (no RMW).
  if(valA){
    u16* obase = (slot ? outg2 : outg) + (size_t)tokA*128 + 4*hi;
    #pragma unroll
    for(int nt=0;nt<4;nt++){
      #pragma unroll
      for(int qq=0;qq<4;qq++){
        float v0 = accO[nt][4*qq+0]*gt;
        float v1 = accO[nt][4*qq+1]*gt;
        float v2 = accO[nt][4*qq+2]*gt;
        float v3 = accO[nt][4*qq+3]*gt;
        u32 w0, w1;
        asm("v_cvt_pk_bf16_f32 %0, %1, %2" : "=v"(w0) : "v"(v0), "v"(v1));
        asm("v_cvt_pk_bf16_f32 %0, %1, %2" : "=v"(w1) : "v"(v2), "v"(v3));
        u32x2 nv; nv.x = w0; nv.y = w1;
        *(u32x2*)(obase + nt*32 + 8*qq) = nv;
      }
    }
  }
}

// head GEMM: A = outg + outg2 (summed bf16 rows), B = WhT2[o][k'].
// wave owns 16 rows, 8-way K-split, no LDS, plain stores to dec8.
__global__ __launch_bounds__(256) void k_head(const u16* __restrict__ Aout,
    const u16* __restrict__ Aout2,
    const u16* __restrict__ WhT2, float* __restrict__ dec8){
  int bid = blockIdx.x;                 // 81 mtiles x 8 ksegs
  int mb = bid>>3, kseg = bid&7;
  int t = threadIdx.x, wid = t>>6, lane = t&63;
  int quad = lane>>4, li = lane&15;
  int r0 = mb*64 + wid*16;
  int rowA = r0 + li; if(rowA >= NRW) rowA = NRW-1;
  size_t abase = (size_t)rowA*DP_ + kseg*1024 + quad*8;
  const u16* aptr  = Aout  + abase;
  const u16* aptr2 = Aout2 + abase;
  const u16* bptr = WhT2 + (size_t)li*DP_  + kseg*1024 + quad*8;
  f32x4 acc[6];
  #pragma unroll
  for(int j=0;j<6;j++) acc[j]=(f32x4){0,0,0,0};
  #pragma unroll 4
  for(int ks=0;ks<32;ks++){
    uint4 va = *(const uint4*)(aptr  + ks*32);
    uint4 vb = *(const uint4*)(aptr2 + ks*32);
    union { uint4 u; bf16x8 v; } vs;
    vs.u.x = bfadd2(va.x, vb.x);
    vs.u.y = bfadd2(va.y, vb.y);
    vs.u.z = bfadd2(va.z, vb.z);
    vs.u.w = bfadd2(va.w, vb.w);
    bf16x8 af = vs.v;
    #pragma unroll
    for(int nt=0;nt<6;nt++){
      bf16x8 bw = *(const bf16x8*)(bptr + (size_t)nt*16*DP_ + ks*32);
      acc[nt] = MFMA16(af, bw, acc[nt]);
    }
  }
  float* dst = dec8 + (size_t)kseg*NRW*96;
  #pragma unroll
  for(int nt=0;nt<6;nt++)
    #pragma unroll
    for(int rg=0;rg<4;rg++){
      int mm = r0 + quad*4 + rg;
      if(mm < NRW) dst[(size_t)mm*96 + nt*16 + li] = acc[nt][rg];
    }
}

// sum 8 k-segments + transpose + bias + denorm
__global__ void k_final(const float* __restrict__ dec8, const float* __restrict__ bhead,
    const float* __restrict__ stdp, const float* __restrict__ meanp, float* __restrict__ outp){
  __shared__ float s[64*97];
  int b = blockIdx.y, v0 = blockIdx.x*64;
  int t = threadIdx.x;
  for(int i=t;i<6144;i+=256){
    int vi = i/96, o = i - vi*96;
    int v = v0+vi;
    float acc = 0.f;
    if(v<NV_){
      size_t base = (size_t)(b*NV_+v)*96 + o;
      #pragma unroll
      for(int ks=0;ks<8;ks++) acc += dec8[(size_t)ks*NRW*96 + base];
    }
    s[vi*97+o] = acc;
  }
  __syncthreads();
  for(int i=t;i<6144;i+=256){
    int o = i>>6, vi = i&63;
    int v = v0+vi;
    if(v<NV_){
      int r = b*NV_+v;
      outp[((size_t)b*96 + o)*NV_ + v] = (s[vi*97+o] + bhead[o])*stdp[r] + meanp[r];
    }
  }
}

// ============ launcher ============
extern "C" void kernel_launch(void* const* d_in, const int* in_sizes, int n_in,
                              void* d_out, int out_size, void* d_ws, size_t ws_size,
                              hipStream_t stream){
  const float* x_enc = (const float*)d_in[0];
  const float* W_val = (const float*)d_in[4];
  const float* W_g   = (const float*)d_in[5];
  const float* W1    = (const float*)d_in[6];
  const float* b1    = (const float*)d_in[7];
  const float* W2    = (const float*)d_in[8];
  const float* b2    = (const float*)d_in[9];
  const float* W_head= (const float*)d_in[10];
  const float* b_head= (const float*)d_in[11];
  float* outp = (float*)d_out;
  char* ws = (char*)d_ws;

  float* meanp = (float*)(ws+OFF_MEAN);
  float* rstdp = (float*)(ws+OFF_RSTD);
  float* stdp  = (float*)(ws+OFF_STD);
  float* xT    = (float*)(ws+OFF_XT);
  float* pe    = (float*)(ws+OFF_PE);
  u16*   W1T   = (u16*)(ws+OFF_W1T);
  u16*   W2T   = (u16*)(ws+OFF_W2T);
  u16*   WhT2  = (u16*)(ws+OFF_WHT);
  u16*   tglob = (u16*)(ws+OFF_T);
  float* dec8  = (float*)(ws+OFF_T);    // aliases tglob (dead after expert gather)
  int*   topip = (int*)(ws+OFF_TOPI);
  float2* gatep= (float2*)(ws+OFF_GATE);
  int*   ci    = (int*)(ws+OFF_CNTR+128);
  int*   btok  = (int*)(ws+OFF_BTOK);
  float* bgt   = (float*)(ws+OFF_BGT);
  u16*   outg  = (u16*)(ws+OFF_OUT);
  u16*   outg2 = (u16*)(ws+OFF_OUT2);   // transients xT/pe/topip/gatep/pg/pib alias this
  double* meand= (double*)(ws+OFF_MEAND);
  double* rstdd= (double*)(ws+OFF_RSTDD);
  double* Wvg  = (double*)(ws+OFF_WVG);
  double* peg  = (double*)(ws+OFF_PEG);
  float* pg    = (float*)(ws+OFF_PG);
  int*   pib   = (int*)(ws+OFF_PI);

  k_xtprep<<<4609, dim3(32,8), 0, stream>>>(x_enc, xT, W_val, W_g, W1, W2, W_head,
                                            pe, Wvg, peg, W1T, W2T, WhT2);
  k_stats<<<NRW, 256, 0, stream>>>(xT, meanp, rstdp, stdp, meand, rstdd);
  k_embgate2<<<2*NRW, 256, 0, stream>>>(xT, meanp, rstdp, meand, rstdd,
                                        W_val, pe, Wvg, peg,
                                        tglob, topip, gatep, pg, pib);
  k_aux<<<1, 1024, 0, stream>>>(pg, pib, ci, outp);
  k_scatter<<<NTOK/1024, 1024, 0, stream>>>(topip, gatep, ci, btok, bgt);
  k_expert<<<2*NBLK_SLOT, 256, 0, stream>>>(tglob, W1T, W2T, b1, b2, ci, btok, bgt,
                                            outg, outg2);
  k_head<<<648, 256, 0, stream>>>(outg, outg2, WhT2, dec8);
  k_final<<<dim3(6,B_), 256, 0, stream>>>(dec8, b_head, stdp, meanp, outp);
}